// Round 2
// baseline (996.655 us; speedup 1.0000x reference)
//
#include <hip/hip_runtime.h>

#define B_   16
#define TXT  32
#define VID  2048
#define D_   256
#define S_   2080
#define SP   2176   // padded sequence (34*64)

typedef unsigned short ushort_t;
typedef __attribute__((ext_vector_type(8))) short short8;
typedef __attribute__((ext_vector_type(4))) short short4v;
typedef __attribute__((ext_vector_type(4))) float f32x4;

__device__ __forceinline__ ushort_t f2bf(float f) {
  unsigned u = __builtin_bit_cast(unsigned, f);
  unsigned r = (u + 0x7FFFu + ((u >> 16) & 1u)) >> 16;   // RNE (finite values)
  return (ushort_t)r;
}
__device__ __forceinline__ float bf2f(ushort_t h) {
  unsigned u = ((unsigned)h) << 16;
  return __builtin_bit_cast(float, u);
}

__device__ __forceinline__ void g2l16(void* lds, const void* g) {
  __builtin_amdgcn_global_load_lds(
      (const __attribute__((address_space(1))) char*)g,
      (__attribute__((address_space(3))) char*)lds, 16, 0, 0);
}

__device__ __forceinline__ f32x4 mfma16(short8 a, short8 b, f32x4 c) {
  return __builtin_amdgcn_mfma_f32_16x16x32_bf16(a, b, c, 0, 0, 0);
}

// ---------------- xpos table: [2048][128] x {cos*s, sin*s, cos/s, sin/s} ----------------
__global__ void tbl_kernel(float* __restrict__ tbl) {
  int idx = blockIdx.x * 256 + threadIdx.x;     // 2048*128 = 262144
  int n = idx >> 7, i = idx & 127;
  float invf = powf(10000.0f, -(float)i / 128.0f);
  float ang = (float)n * invf;
  float s, co;
  sincosf(ang, &s, &co);
  float sv = ((float)(2 * i) + 102.4f) / 358.4f;   // (2i + 0.4*256)/(1.4*256)
  float sc = powf(sv, (float)n / 512.0f);
  float4 r;
  r.x = co * sc; r.y = s * sc; r.z = co / sc; r.w = s / sc;
  *(float4*)(tbl + (size_t)idx * 4) = r;
}

// ---------------- sigmoid mask (bf16) + sparsity loss ----------------
__global__ void sig_loss_kernel(const float* __restrict__ learn, ushort_t* __restrict__ sigp,
                                float* __restrict__ loss) {
  const int tid = threadIdx.x;
  const int base = (blockIdx.x * 256 + tid) * 8;
  float4 v0 = *(const float4*)(learn + base);
  float4 v1 = *(const float4*)(learn + base + 4);
  float vals[8] = {v0.x, v0.y, v0.z, v0.w, v1.x, v1.y, v1.z, v1.w};
  float acc = 0.f;
  short8 sh;
  #pragma unroll
  for (int j = 0; j < 8; ++j) {
    int idx = base + j;
    float s = 1.0f / (1.0f + expf(-vals[j]));
    sh[j] = (short)f2bf(s);
    int rr = idx >> 11, cc = idx & 2047;
    if (rr != cc) acc += s;
  }
  *(short8*)(sigp + base) = sh;
  __shared__ float red[256];
  red[tid] = acc;
  __syncthreads();
  #pragma unroll
  for (int st = 128; st > 0; st >>= 1) {
    if (tid < st) red[tid] += red[tid + st];
    __syncthreads();
  }
  if (tid == 0) atomicAdd(loss, red[0] * (1.0f / 4194304.0f));
}

// ---------------- weight transpose: WT[mat][n][k] = W[k][n] (bf16) ----------------
__global__ void wt_kernel(const float* __restrict__ Wq, const float* __restrict__ Wk,
                          const float* __restrict__ Wv, ushort_t* __restrict__ WT) {
  __shared__ float t[64][68];
  const int k0 = blockIdx.x * 64, n0 = blockIdx.y * 64, mt = blockIdx.z;
  const float* W = (mt == 0) ? Wq : (mt == 1) ? Wk : Wv;
  int tid = threadIdx.x;
  int r = tid >> 4, cq = (tid & 15) * 4;
  #pragma unroll
  for (int m = 0; m < 4; ++m) {
    int k = m * 16 + r;
    float4 v = *(const float4*)(W + (size_t)(k0 + k) * 256 + n0 + cq);
    t[k][cq] = v.x; t[k][cq + 1] = v.y; t[k][cq + 2] = v.z; t[k][cq + 3] = v.w;
  }
  __syncthreads();
  #pragma unroll
  for (int m = 0; m < 4; ++m) {
    int n = m * 16 + r;
    short4v h;
    h[0] = (short)f2bf(t[cq + 0][n]);
    h[1] = (short)f2bf(t[cq + 1][n]);
    h[2] = (short)f2bf(t[cq + 2][n]);
    h[3] = (short)f2bf(t[cq + 3][n]);
    *(short4v*)(WT + ((size_t)mt * D_ + n0 + n) * D_ + k0 + cq) = h;
  }
}

// ---------------- txt rows: Q/K = (pos+x)W, V = xW ----------------
__global__ void txt_kernel(const float* __restrict__ src,
                           const float* __restrict__ Wq, const float* __restrict__ Wk,
                           const float* __restrict__ Wv,
                           ushort_t* __restrict__ Qp, ushort_t* __restrict__ Kp,
                           ushort_t* __restrict__ VTp) {
  __shared__ float a_s[8][256];
  __shared__ float x_s[8][256];
  const int tg = blockIdx.x;       // 0..3  (8 rows each)
  const int b  = blockIdx.y;
  const int c  = threadIdx.x;      // 0..255
  #pragma unroll
  for (int t = 0; t < 8; ++t) {
    int row = tg * 8 + t;
    float x = src[((size_t)b * S_ + row) * D_ + c];
    float xe = (float)(row + 1) * (6.283185307179586f / (32.0f + 1e-6f));
    int i = c >> 1;
    float dimt = powf(10000.0f, (2.0f * (float)i) / 256.0f);
    float ang = xe / dimt;
    float pv = (c & 1) ? cosf(ang) : sinf(ang);
    x_s[t][c] = x;
    a_s[t][c] = x + pv;
  }
  __syncthreads();
  float q[8] = {0,0,0,0,0,0,0,0}, k[8] = {0,0,0,0,0,0,0,0}, v[8] = {0,0,0,0,0,0,0,0};
  for (int kk = 0; kk < 256; ++kk) {
    float wq = Wq[(size_t)kk * 256 + c];
    float wk = Wk[(size_t)kk * 256 + c];
    float wv = Wv[(size_t)kk * 256 + c];
    #pragma unroll
    for (int t = 0; t < 8; ++t) {
      q[t] = fmaf(a_s[t][kk], wq, q[t]);
      k[t] = fmaf(a_s[t][kk], wk, k[t]);
      v[t] = fmaf(x_s[t][kk], wv, v[t]);
    }
  }
  #pragma unroll
  for (int t = 0; t < 8; ++t) {
    int row = tg * 8 + t;
    Qp[((size_t)b * SP + row) * D_ + c] = f2bf(q[t]);
    Kp[((size_t)b * SP + row) * D_ + c] = f2bf(k[t]);
    VTp[((size_t)b * D_ + c) * SP + row] = f2bf(v[t]);
  }
}

// ---------------- vid projection GEMM (+xpos epilogue, V transposed) ----------------
__global__ __launch_bounds__(256, 2) void vid_gemm(
    const float* __restrict__ src, const ushort_t* __restrict__ WT,
    const float* __restrict__ tbl,
    ushort_t* __restrict__ Qp, ushort_t* __restrict__ Kp, ushort_t* __restrict__ VTp) {
  __shared__ __align__(16) ushort_t ldsA[64 * 64];
  __shared__ __align__(16) ushort_t ldsB[64 * 64];

  const int rt = blockIdx.x;            // 0..31 row tiles (vid rows)
  const int b  = blockIdx.y;
  const int ct = blockIdx.z;            // 0..11 col tiles (3 mats x 4)
  const int nt = ct >> 2;
  const int n0 = (ct & 3) * 64;
  const int tid = threadIdx.x;
  const int wv = tid >> 6, lane = tid & 63, l15 = lane & 15, l4 = lane >> 4;

  f32x4 acc[4];
  #pragma unroll
  for (int t2 = 0; t2 < 4; ++t2) { acc[t2][0] = 0.f; acc[t2][1] = 0.f; acc[t2][2] = 0.f; acc[t2][3] = 0.f; }

  for (int kk = 0; kk < 256; kk += 64) {
    #pragma unroll
    for (int m = 0; m < 4; ++m) {                 // A tile 64x64 (f32->bf16, swizzled)
      int q = m * 256 + tid;
      int r = q >> 4;
      int kc = (q & 15) * 4;
      const float4 v = *(const float4*)(src + ((size_t)b * S_ + TXT + rt * 64 + r) * D_ + kk + kc);
      short4v h;
      h[0] = (short)f2bf(v.x); h[1] = (short)f2bf(v.y);
      h[2] = (short)f2bf(v.z); h[3] = (short)f2bf(v.w);
      int off = ((r << 7) + (kc << 1)) ^ ((r & 7) << 4);
      *(short4v*)((char*)ldsA + off) = h;
    }
    #pragma unroll
    for (int m = 0; m < 2; ++m) {                 // B^T tile 64x64 via global_load_lds
      int p = (m * 256 + tid) * 16;
      int nl = p >> 7;
      int c = (p & 127) ^ ((nl & 7) << 4);
      g2l16((char*)ldsB + p, (const char*)(WT + ((size_t)nt * D_ + n0 + nl) * D_ + kk) + c);
    }
    __syncthreads();
    #pragma unroll
    for (int ks = 0; ks < 2; ++ks) {
      int ar = wv * 16 + l15;
      int aoff = ((ar << 7) + ((ks * 32 + l4 * 8) << 1)) ^ ((ar & 7) << 4);
      short8 av = *(const short8*)((const char*)ldsA + aoff);
      #pragma unroll
      for (int t2 = 0; t2 < 4; ++t2) {
        int nl = t2 * 16 + l15;
        int boff = ((nl << 7) + ((ks * 32 + l4 * 8) << 1)) ^ ((nl & 7) << 4);
        short8 bv = *(const short8*)((const char*)ldsB + boff);
        acc[t2] = mfma16(av, bv, acc[t2]);
      }
    }
    __syncthreads();
  }

  const int rowl = wv * 16 + l4 * 4;
  if (nt < 2) {
    // xpos rotary epilogue; even col: x*cs - x_partner*ss ; odd: x*cs + x_partner*ss
    ushort_t* dst = (nt == 0) ? Qp : Kp;
    #pragma unroll
    for (int t2 = 0; t2 < 4; ++t2) {
      int c = n0 + t2 * 16 + l15;
      #pragma unroll
      for (int r = 0; r < 4; ++r) {
        int n = rt * 64 + rowl + r;          // vid position 0..2047
        float x = acc[t2][r];
        float xp = __shfl_xor(x, 1);
        const float4 tb = *(const float4*)(tbl + ((size_t)n * 128 + (c >> 1)) * 4);
        float cs = (nt == 0) ? tb.x : tb.z;
        float ss = (nt == 0) ? tb.y : tb.w;
        float val = (c & 1) ? fmaf(x, cs, xp * ss) : fmaf(x, cs, -xp * ss);
        dst[((size_t)b * SP + TXT + n) * D_ + c] = f2bf(val);
      }
    }
  } else {
    // V: transpose via LDS then coalesced store to VT
    #pragma unroll
    for (int t2 = 0; t2 < 4; ++t2)
      #pragma unroll
      for (int r = 0; r < 4; ++r) {
        int rr = rowl + r;
        int cc = t2 * 16 + l15;
        int off = ((rr << 7) + (cc << 1)) ^ ((rr & 7) << 4);
        *(ushort_t*)((char*)ldsA + off) = f2bf(acc[t2][r]);
      }
    __syncthreads();
    int n = tid >> 2;
    int rc = (tid & 3) * 16;
    short8 o0, o1;
    #pragma unroll
    for (int j = 0; j < 8; ++j) {
      int rr = rc + j;
      int off = ((rr << 7) + (n << 1)) ^ ((rr & 7) << 4);
      o0[j] = *(const short*)((const char*)ldsA + off);
    }
    #pragma unroll
    for (int j = 0; j < 8; ++j) {
      int rr = rc + 8 + j;
      int off = ((rr << 7) + (n << 1)) ^ ((rr & 7) << 4);
      o1[j] = *(const short*)((const char*)ldsA + off);
    }
    ushort_t* dst = VTp + ((size_t)b * D_ + n0 + n) * SP + TXT + rt * 64 + rc;
    *(short8*)dst = o0;
    *(short8*)(dst + 8) = o1;
  }
}

// ---------------- fused masked attention: out = (Q K^T * M) V ----------------
// Barrier-free: K/V fragments read directly from global (L2/L3-resident),
// P kept in wave-private LDS slice. 12 waves/CU target for latency hiding.
__global__ __launch_bounds__(256, 3) void attn_kernel(
    const ushort_t* __restrict__ Qp, const ushort_t* __restrict__ Kp,
    const ushort_t* __restrict__ VTp, const ushort_t* __restrict__ sigp,
    float* __restrict__ out) {
  __shared__ __align__(16) ushort_t ldsP[4][16 * 64];   // per-wave [16][64] bf16, swizzled

  // bijective XCD swizzle: 528 blocks = 8 XCDs x 66; batch-major so each XCD
  // works on ~2 batches -> K/V (2.2MB/batch) stays in that XCD's 4MB L2.
  const int flat = blockIdx.x;
  const int wgid = (flat & 7) * 66 + (flat >> 3);
  const int b  = wgid / 33;
  const int qt = wgid % 33;

  const int tid = threadIdx.x;
  const int wv = tid >> 6;
  const int lane = tid & 63;
  const int l15 = lane & 15;
  const int l4  = lane >> 4;

  const ushort_t* Kb = Kp + (size_t)b * SP * D_;
  const ushort_t* Vb = VTp + (size_t)b * D_ * SP;
  ushort_t* Pw = &ldsP[wv][0];

  // Q fragments: wave owns q rows [qt*64 + wv*16, +16)
  short8 qf[8];
  {
    const ushort_t* qrow = Qp + ((size_t)b * SP + qt * 64 + wv * 16 + l15) * D_ + l4 * 8;
    #pragma unroll
    for (int ks = 0; ks < 8; ++ks) qf[ks] = *(const short8*)(qrow + ks * 32);
  }

  f32x4 oacc[16];
  #pragma unroll
  for (int dt = 0; dt < 16; ++dt) { oacc[dt][0] = 0.f; oacc[dt][1] = 0.f; oacc[dt][2] = 0.f; oacc[dt][3] = 0.f; }

  for (int kt = 0; kt < 33; ++kt) {
    const int kv0 = kt * 64;

    // S = Q K^T : K fragments straight from global (16 lanes x 16B = 64B rows)
    f32x4 sacc[4];
    #pragma unroll
    for (int ctt = 0; ctt < 4; ++ctt) { sacc[ctt][0] = 0.f; sacc[ctt][1] = 0.f; sacc[ctt][2] = 0.f; sacc[ctt][3] = 0.f; }
    __builtin_amdgcn_s_setprio(1);
    #pragma unroll
    for (int ks = 0; ks < 8; ++ks) {
      #pragma unroll
      for (int ctt = 0; ctt < 4; ++ctt) {
        short8 kf = *(const short8*)(Kb + (size_t)(kv0 + ctt * 16 + l15) * D_ + ks * 32 + l4 * 8);
        sacc[ctt] = mfma16(qf[ks], kf, sacc[ctt]);
      }
    }
    __builtin_amdgcn_s_setprio(0);

    // mask + P (bf16, wave-private LDS slice -> no __syncthreads anywhere)
    #pragma unroll
    for (int ctt = 0; ctt < 4; ++ctt) {
      int kvg = kv0 + ctt * 16 + l15;
      bool kvv = (kvg >= TXT) && (kvg < S_);
      #pragma unroll
      for (int r = 0; r < 4; ++r) {
        int qg = qt * 64 + wv * 16 + l4 * 4 + r;
        float mv = 1.0f;
        if (kvv && qg >= TXT && qg < S_)
          mv = bf2f(sigp[(size_t)(qg - TXT) * VID + (kvg - TXT)]);
        float pvv = sacc[ctt][r] * mv;
        int prow = l4 * 4 + r;
        int pcol = ctt * 16 + l15;
        int off = ((prow << 7) + (pcol << 1)) ^ ((prow & 7) << 4);
        *(ushort_t*)((char*)Pw + off) = f2bf(pvv);
      }
    }

    // O += P V : V^T fragments straight from global
    #pragma unroll
    for (int ks2 = 0; ks2 < 2; ++ks2) {
      int poff = ((l15 << 7) + ((ks2 * 32 + l4 * 8) << 1)) ^ ((l15 & 7) << 4);
      short8 pf = *(const short8*)((const char*)Pw + poff);
      __builtin_amdgcn_s_setprio(1);
      #pragma unroll
      for (int dt = 0; dt < 16; ++dt) {
        short8 vf = *(const short8*)(Vb + (size_t)(dt * 16 + l15) * SP + kv0 + ks2 * 32 + l4 * 8);
        oacc[dt] = mfma16(pf, vf, oacc[dt]);
      }
      __builtin_amdgcn_s_setprio(0);
    }
  }

  #pragma unroll
  for (int dt = 0; dt < 16; ++dt) {
    int dd = dt * 16 + l15;
    #pragma unroll
    for (int r = 0; r < 4; ++r) {
      int qg = qt * 64 + wv * 16 + l4 * 4 + r;
      if (qg < S_)
        out[((size_t)b * S_ + qg) * D_ + dd] = oacc[dt][r];
    }
  }
}

extern "C" void kernel_launch(void* const* d_in, const int* in_sizes, int n_in,
                              void* d_out, int out_size, void* d_ws, size_t ws_size,
                              hipStream_t stream) {
  (void)in_sizes; (void)n_in; (void)out_size; (void)ws_size;
  const float* src   = (const float*)d_in[0];
  const float* learn = (const float*)d_in[1];
  const float* Wtq = (const float*)d_in[2];
  const float* Wtk = (const float*)d_in[3];
  const float* Wtv = (const float*)d_in[4];
  const float* Wvq = (const float*)d_in[5];
  const float* Wvk = (const float*)d_in[6];
  const float* Wvv = (const float*)d_in[7];
  float* out = (float*)d_out;

  char* ws = (char*)d_ws;
  const size_t QKV_ONE = (size_t)B_ * SP * D_ * 2;         // 17,825,792 B each
  const size_t QP_OFF  = 0;
  const size_t KP_OFF  = QP_OFF + QKV_ONE;
  const size_t VT_OFF  = KP_OFF + QKV_ONE;
  const size_t SIG_OFF = VT_OFF + QKV_ONE;                  // 53,477,376
  const size_t TBL_OFF = SIG_OFF + (size_t)VID * VID * 2;   // +8,388,608
  const size_t WT_OFF  = TBL_OFF + (size_t)VID * 128 * 4 * sizeof(float); // +4,194,304
  // total ws use: WT_OFF + 393,216 = 66,453,504 B

  ushort_t* Qp   = (ushort_t*)(ws + QP_OFF);
  ushort_t* Kp   = (ushort_t*)(ws + KP_OFF);
  ushort_t* VTp  = (ushort_t*)(ws + VT_OFF);
  ushort_t* sigp = (ushort_t*)(ws + SIG_OFF);
  float*    tbl  = (float*)(ws + TBL_OFF);
  ushort_t* WT   = (ushort_t*)(ws + WT_OFF);

  float* loss = out + (size_t)B_ * S_ * D_;

  hipMemsetAsync(ws, 0, SIG_OFF, stream);          // zero Q/K/VT (padding rows)
  hipMemsetAsync(loss, 0, sizeof(float), stream);

  tbl_kernel<<<1024, 256, 0, stream>>>(tbl);
  sig_loss_kernel<<<2048, 256, 0, stream>>>(learn, sigp, loss);
  wt_kernel<<<dim3(4, 4, 3), 256, 0, stream>>>(Wvq, Wvk, Wvv, WT);
  txt_kernel<<<dim3(4, B_), 256, 0, stream>>>(src, Wtq, Wtk, Wtv, Qp, Kp, VTp);
  vid_gemm<<<dim3(32, B_, 12), 256, 0, stream>>>(src, WT, tbl, Qp, Kp, VTp);
  attn_kernel<<<dim3(528), 256, 0, stream>>>(Qp, Kp, VTp, sigp, out);
}

// Round 3
// 747.142 us; speedup vs baseline: 1.3340x; 1.3340x over previous
//
#include <hip/hip_runtime.h>

#define B_   16
#define TXT  32
#define VID  2048
#define D_   256
#define S_   2080
#define SP   2176   // padded sequence rows for Q
#define NKT  34     // kv tiles (64 each) in K/V layouts
#define ITERS 33    // kv tiles actually processed (covers 2112 >= 2080)

typedef unsigned short ushort_t;
typedef __attribute__((ext_vector_type(8))) short short8;
typedef __attribute__((ext_vector_type(4))) short short4v;
typedef __attribute__((ext_vector_type(4))) float f32x4;
typedef __attribute__((ext_vector_type(16))) float f32x16;

__device__ __forceinline__ ushort_t f2bf(float f) {
  unsigned u = __builtin_bit_cast(unsigned, f);
  unsigned r = (u + 0x7FFFu + ((u >> 16) & 1u)) >> 16;   // RNE (finite values)
  return (ushort_t)r;
}
__device__ __forceinline__ float bf2f(ushort_t h) {
  unsigned u = ((unsigned)h) << 16;
  return __builtin_bit_cast(float, u);
}

__device__ __forceinline__ void g2l16(void* lds, const void* g) {
  __builtin_amdgcn_global_load_lds(
      (const __attribute__((address_space(1))) char*)g,
      (__attribute__((address_space(3))) char*)lds, 16, 0, 0);
}

__device__ __forceinline__ f32x4 mfma16(short8 a, short8 b, f32x4 c) {
  return __builtin_amdgcn_mfma_f32_16x16x32_bf16(a, b, c, 0, 0, 0);
}
__device__ __forceinline__ f32x16 mfma32(short8 a, short8 b, f32x16 c) {
  return __builtin_amdgcn_mfma_f32_32x32x16_bf16(a, b, c, 0, 0, 0);
}

// K layout (per batch, per 64-kv tile, 32KB):   [kstep16][64 kv][16 us]   (d-chunk rows of 32B)
// V layout (per batch, per 64-kv tile, 32KB):   [kvstep4][256 d][16 us]   (kv-chunk rows of 32B)
// tile base (ushorts): (b*NKT + ktile) << 14

// ---------------- xpos table: [2048][128] x {cos*s, sin*s, cos/s, sin/s} ----------------
__global__ void tbl_kernel(float* __restrict__ tbl) {
  int idx = blockIdx.x * 256 + threadIdx.x;     // 2048*128 = 262144
  int n = idx >> 7, i = idx & 127;
  float invf = powf(10000.0f, -(float)i / 128.0f);
  float ang = (float)n * invf;
  float s, co;
  sincosf(ang, &s, &co);
  float sv = ((float)(2 * i) + 102.4f) / 358.4f;   // (2i + 0.4*256)/(1.4*256)
  float sc = powf(sv, (float)n / 512.0f);
  float4 r;
  r.x = co * sc; r.y = s * sc; r.z = co / sc; r.w = s / sc;
  *(float4*)(tbl + (size_t)idx * 4) = r;
}

// ---------------- sigmoid mask (bf16) + sparsity loss ----------------
__global__ void sig_loss_kernel(const float* __restrict__ learn, ushort_t* __restrict__ sigp,
                                float* __restrict__ loss) {
  const int tid = threadIdx.x;
  const int base = (blockIdx.x * 256 + tid) * 8;
  float4 v0 = *(const float4*)(learn + base);
  float4 v1 = *(const float4*)(learn + base + 4);
  float vals[8] = {v0.x, v0.y, v0.z, v0.w, v1.x, v1.y, v1.z, v1.w};
  float acc = 0.f;
  short8 sh;
  #pragma unroll
  for (int j = 0; j < 8; ++j) {
    int idx = base + j;
    float s = 1.0f / (1.0f + expf(-vals[j]));
    sh[j] = (short)f2bf(s);
    int rr = idx >> 11, cc = idx & 2047;
    if (rr != cc) acc += s;
  }
  *(short8*)(sigp + base) = sh;
  __shared__ float red[256];
  red[tid] = acc;
  __syncthreads();
  #pragma unroll
  for (int st = 128; st > 0; st >>= 1) {
    if (tid < st) red[tid] += red[tid + st];
    __syncthreads();
  }
  if (tid == 0) atomicAdd(loss, red[0] * (1.0f / 4194304.0f));
}

// ---------------- weight transpose: WT[mat][n][k] = W[k][n] (bf16) ----------------
__global__ void wt_kernel(const float* __restrict__ Wq, const float* __restrict__ Wk,
                          const float* __restrict__ Wv, ushort_t* __restrict__ WT) {
  __shared__ float t[64][68];
  const int k0 = blockIdx.x * 64, n0 = blockIdx.y * 64, mt = blockIdx.z;
  const float* W = (mt == 0) ? Wq : (mt == 1) ? Wk : Wv;
  int tid = threadIdx.x;
  int r = tid >> 4, cq = (tid & 15) * 4;
  #pragma unroll
  for (int m = 0; m < 4; ++m) {
    int k = m * 16 + r;
    float4 v = *(const float4*)(W + (size_t)(k0 + k) * 256 + n0 + cq);
    t[k][cq] = v.x; t[k][cq + 1] = v.y; t[k][cq + 2] = v.z; t[k][cq + 3] = v.w;
  }
  __syncthreads();
  #pragma unroll
  for (int m = 0; m < 4; ++m) {
    int n = m * 16 + r;
    short4v h;
    h[0] = (short)f2bf(t[cq + 0][n]);
    h[1] = (short)f2bf(t[cq + 1][n]);
    h[2] = (short)f2bf(t[cq + 2][n]);
    h[3] = (short)f2bf(t[cq + 3][n]);
    *(short4v*)(WT + ((size_t)mt * D_ + n0 + n) * D_ + k0 + cq) = h;
  }
}

// ---------------- txt rows: Q/K = (pos+x)W, V = xW ----------------
__global__ void txt_kernel(const float* __restrict__ src,
                           const float* __restrict__ Wq, const float* __restrict__ Wk,
                           const float* __restrict__ Wv,
                           ushort_t* __restrict__ Qp, ushort_t* __restrict__ Ks,
                           ushort_t* __restrict__ VTs) {
  __shared__ float a_s[8][256];
  __shared__ float x_s[8][256];
  const int tg = blockIdx.x;       // 0..3  (8 rows each)
  const int b  = blockIdx.y;
  const int c  = threadIdx.x;      // 0..255
  #pragma unroll
  for (int t = 0; t < 8; ++t) {
    int row = tg * 8 + t;
    float x = src[((size_t)b * S_ + row) * D_ + c];
    float xe = (float)(row + 1) * (6.283185307179586f / (32.0f + 1e-6f));
    int i = c >> 1;
    float dimt = powf(10000.0f, (2.0f * (float)i) / 256.0f);
    float ang = xe / dimt;
    float pv = (c & 1) ? cosf(ang) : sinf(ang);
    x_s[t][c] = x;
    a_s[t][c] = x + pv;
  }
  __syncthreads();
  float q[8] = {0,0,0,0,0,0,0,0}, k[8] = {0,0,0,0,0,0,0,0}, v[8] = {0,0,0,0,0,0,0,0};
  for (int kk = 0; kk < 256; ++kk) {
    float wq = Wq[(size_t)kk * 256 + c];
    float wk = Wk[(size_t)kk * 256 + c];
    float wv = Wv[(size_t)kk * 256 + c];
    #pragma unroll
    for (int t = 0; t < 8; ++t) {
      q[t] = fmaf(a_s[t][kk], wq, q[t]);
      k[t] = fmaf(a_s[t][kk], wk, k[t]);
      v[t] = fmaf(x_s[t][kk], wv, v[t]);
    }
  }
  #pragma unroll
  for (int t = 0; t < 8; ++t) {
    int row = tg * 8 + t;          // kv row (txt rows are kv 0..31, ktile 0)
    Qp[((size_t)b * SP + row) * D_ + c] = f2bf(q[t]);
    Ks[(((size_t)(b * NKT)) << 14) + (c >> 4) * 1024 + row * 16 + (c & 15)] = f2bf(k[t]);
    VTs[(((size_t)(b * NKT)) << 14) + (row >> 4) * 4096 + c * 16 + (row & 15)] = f2bf(v[t]);
  }
}

// ---------------- vid projection GEMM (+xpos epilogue, subtiled K/V out) ----------------
__global__ __launch_bounds__(256, 2) void vid_gemm(
    const float* __restrict__ src, const ushort_t* __restrict__ WT,
    const float* __restrict__ tbl,
    ushort_t* __restrict__ Qp, ushort_t* __restrict__ Ks, ushort_t* __restrict__ VTs) {
  __shared__ __align__(16) ushort_t ldsA[64 * 64];
  __shared__ __align__(16) ushort_t ldsB[64 * 64];

  const int rt = blockIdx.x;            // 0..31 row tiles (vid rows)
  const int b  = blockIdx.y;
  const int ct = blockIdx.z;            // 0..11 col tiles (3 mats x 4)
  const int nt = ct >> 2;
  const int n0 = (ct & 3) * 64;
  const int tid = threadIdx.x;
  const int wv = tid >> 6, lane = tid & 63, l15 = lane & 15, l4 = lane >> 4;

  f32x4 acc[4];
  #pragma unroll
  for (int t2 = 0; t2 < 4; ++t2) { acc[t2][0] = 0.f; acc[t2][1] = 0.f; acc[t2][2] = 0.f; acc[t2][3] = 0.f; }

  for (int kk = 0; kk < 256; kk += 64) {
    #pragma unroll
    for (int m = 0; m < 4; ++m) {                 // A tile 64x64 (f32->bf16, swizzled)
      int q = m * 256 + tid;
      int r = q >> 4;
      int kc = (q & 15) * 4;
      const float4 v = *(const float4*)(src + ((size_t)b * S_ + TXT + rt * 64 + r) * D_ + kk + kc);
      short4v h;
      h[0] = (short)f2bf(v.x); h[1] = (short)f2bf(v.y);
      h[2] = (short)f2bf(v.z); h[3] = (short)f2bf(v.w);
      int off = ((r << 7) + (kc << 1)) ^ ((r & 7) << 4);
      *(short4v*)((char*)ldsA + off) = h;
    }
    #pragma unroll
    for (int m = 0; m < 2; ++m) {                 // B^T tile 64x64 via global_load_lds
      int p = (m * 256 + tid) * 16;
      int nl = p >> 7;
      int c = (p & 127) ^ ((nl & 7) << 4);
      g2l16((char*)ldsB + p, (const char*)(WT + ((size_t)nt * D_ + n0 + nl) * D_ + kk) + c);
    }
    __syncthreads();
    #pragma unroll
    for (int ks = 0; ks < 2; ++ks) {
      int ar = wv * 16 + l15;
      int aoff = ((ar << 7) + ((ks * 32 + l4 * 8) << 1)) ^ ((ar & 7) << 4);
      short8 av = *(const short8*)((const char*)ldsA + aoff);
      #pragma unroll
      for (int t2 = 0; t2 < 4; ++t2) {
        int nl = t2 * 16 + l15;
        int boff = ((nl << 7) + ((ks * 32 + l4 * 8) << 1)) ^ ((nl & 7) << 4);
        short8 bv = *(const short8*)((const char*)ldsB + boff);
        acc[t2] = mfma16(av, bv, acc[t2]);
      }
    }
    __syncthreads();
  }

  const int rowl = wv * 16 + l4 * 4;
  if (nt < 2) {
    // xpos rotary epilogue; even col: x*cs - x_partner*ss ; odd: x*cs + x_partner*ss
    #pragma unroll
    for (int t2 = 0; t2 < 4; ++t2) {
      int c = n0 + t2 * 16 + l15;
      #pragma unroll
      for (int r = 0; r < 4; ++r) {
        int n = rt * 64 + rowl + r;          // vid position 0..2047
        float x = acc[t2][r];
        float xp = __shfl_xor(x, 1);
        const float4 tb = *(const float4*)(tbl + ((size_t)n * 128 + (c >> 1)) * 4);
        float cs = (nt == 0) ? tb.x : tb.z;
        float ss = (nt == 0) ? tb.y : tb.w;
        float val = (c & 1) ? fmaf(x, cs, xp * ss) : fmaf(x, cs, -xp * ss);
        if (nt == 0) {
          Qp[((size_t)b * SP + TXT + n) * D_ + c] = f2bf(val);
        } else {
          int kvg = TXT + n;
          Ks[(((size_t)(b * NKT + (kvg >> 6))) << 14) + (c >> 4) * 1024 + (kvg & 63) * 16 + (c & 15)] = f2bf(val);
        }
      }
    }
  } else {
    // V: transpose via LDS then coalesced store to subtiled VTs
    #pragma unroll
    for (int t2 = 0; t2 < 4; ++t2)
      #pragma unroll
      for (int r = 0; r < 4; ++r) {
        int rr = rowl + r;
        int cc = t2 * 16 + l15;
        int off = ((rr << 7) + (cc << 1)) ^ ((rr & 7) << 4);
        *(ushort_t*)((char*)ldsA + off) = f2bf(acc[t2][r]);
      }
    __syncthreads();
    int n = tid >> 2;                 // local d 0..63
    int rc = (tid & 3) * 16;          // local vid row chunk
    short8 o0, o1;
    #pragma unroll
    for (int j = 0; j < 8; ++j) {
      int rr = rc + j;
      int off = ((rr << 7) + (n << 1)) ^ ((rr & 7) << 4);
      o0[j] = *(const short*)((const char*)ldsA + off);
    }
    #pragma unroll
    for (int j = 0; j < 8; ++j) {
      int rr = rc + 8 + j;
      int off = ((rr << 7) + (n << 1)) ^ ((rr & 7) << 4);
      o1[j] = *(const short*)((const char*)ldsA + off);
    }
    int d = n0 + n;
    int kvg0 = TXT + rt * 64 + rc;    // 16-aligned
    size_t base = (((size_t)(b * NKT + (kvg0 >> 6))) << 14) + ((kvg0 >> 4) & 3) * 4096 + d * 16;
    *(short8*)(VTs + base) = o0;
    *(short8*)(VTs + base + 8) = o1;
  }
}

// ---------------- fused masked attention: out = (Q K^T * M) V ----------------
// 4 waves. QK: wave (qh,kh) computes S quarter [qh*32..][kh*32..] with 32x32x16 MFMA,
// Q static in regs. PV: wave wid owns d-slice wid*64, all 64 q. P via 8KB LDS.
// K double-buffered via linear global_load_lds from pre-subtiled layout; counted vmcnt.
__global__ __launch_bounds__(256) void attn_kernel(
    const ushort_t* __restrict__ Qp, const ushort_t* __restrict__ Ks,
    const ushort_t* __restrict__ VTs, const ushort_t* __restrict__ sigp,
    float* __restrict__ out) {
  __shared__ __align__(16) ushort_t Kb[2][16384];   // 2 x 32KB
  __shared__ __align__(16) ushort_t Vb[16384];      // 32KB
  __shared__ __align__(16) ushort_t Pb[4096];       // 8KB  [ks4][64 q][16 us], XOR swz

  const int flat = blockIdx.x;                      // 528 = 8 * 66, bijective XCD swizzle
  const int wg = (flat & 7) * 66 + (flat >> 3);
  const int b  = wg / ITERS;
  const int qt = wg % ITERS;
  const int tid = threadIdx.x;
  const int wid = tid >> 6, lane = tid & 63;
  const int l31 = lane & 31, l5 = lane >> 5;
  const int qh = wid >> 1, kh = wid & 1, d0 = wid * 64;
  const int q0 = qt * 64;

  // static Q fragments: rows q0+qh*32+l31, k-chunks per kstep
  short8 qf[16];
  {
    const ushort_t* qrow = Qp + ((size_t)b * SP + q0 + qh * 32 + l31) * D_ + l5 * 8;
    #pragma unroll
    for (int ks = 0; ks < 16; ++ks) qf[ks] = *(const short8*)(qrow + ks * 16);
  }

  f32x16 oacc[2][2];
  #pragma unroll
  for (int i = 0; i < 2; ++i)
    #pragma unroll
    for (int j = 0; j < 2; ++j)
      #pragma unroll
      for (int r = 0; r < 16; ++r) oacc[i][j][r] = 0.f;

  const char* ksrc = (const char*)Ks + (((size_t)(b * NKT)) << 15);
  const char* vsrc = (const char*)VTs + (((size_t)(b * NKT)) << 15);

  // prologue: stage K0 then V0 (linear copies)
  #pragma unroll
  for (int m = 0; m < 8; ++m) { int s = m * 256 + tid; g2l16((char*)Kb[0] + s * 16, ksrc + s * 16); }
  #pragma unroll
  for (int m = 0; m < 8; ++m) { int s = m * 256 + tid; g2l16((char*)Vb + s * 16, vsrc + s * 16); }
  asm volatile("s_waitcnt vmcnt(8)" ::: "memory");   // K0 done; V0 may fly
  __builtin_amdgcn_sched_barrier(0);
  __builtin_amdgcn_s_barrier();
  __builtin_amdgcn_sched_barrier(0);

  const int pswz = ((l31 >> 2) & 3) << 5;

  for (int kt = 0; kt < ITERS; ++kt) {
    const int cur = kt & 1;
    const int kvg = kt * 64 + kh * 32 + l31;

    // masks for this iter (issued before next-tile stage so their waits don't drain it)
    float mv[16];
    {
      unsigned ki = (unsigned)(kvg - TXT);
      #pragma unroll
      for (int reg = 0; reg < 16; ++reg) {
        int qg = q0 + qh * 32 + (reg & 3) + 8 * (reg >> 2) + 4 * l5;
        unsigned qi = (unsigned)(qg - TXT);
        bool ok = (qi < (unsigned)VID) && (ki < (unsigned)VID);
        size_t idx = ok ? ((size_t)qi * VID + ki) : 0;
        ushort_t mraw = sigp[idx];
        mv[reg] = ok ? bf2f(mraw) : 1.0f;
      }
    }

    // stage K(kt+1) -> other buffer (tile ITERS..NKT-1 is zero padding, safe)
    {
      const char* src = ksrc + ((size_t)(kt + 1) << 15);
      #pragma unroll
      for (int m = 0; m < 8; ++m) { int s = m * 256 + tid; g2l16((char*)Kb[cur ^ 1] + s * 16, src + s * 16); }
    }

    // QK: S quarter
    f32x16 sacc;
    #pragma unroll
    for (int r = 0; r < 16; ++r) sacc[r] = 0.f;
    #pragma unroll
    for (int ks = 0; ks < 16; ++ks) {
      short8 kf = *(const short8*)((const char*)Kb[cur] + ks * 2048 + (kh * 32 + l31) * 32 + l5 * 16);
      sacc = mfma32(qf[ks], kf, sacc);
    }
    // mask + P write (bf16, swizzled)
    #pragma unroll
    for (int reg = 0; reg < 16; ++reg) {
      int qloc = qh * 32 + (reg & 3) + 8 * (reg >> 2) + 4 * l5;
      int kvl = kh * 32 + l31;
      int off = ((kvl >> 4) * 2048 + qloc * 32 + (kvl & 15) * 2) ^ ((((unsigned)qloc >> 2) & 3) << 5);
      *(ushort_t*)((char*)Pb + off) = f2bf(sacc[reg] * mv[reg]);
    }

    asm volatile("s_waitcnt vmcnt(8) lgkmcnt(0)" ::: "memory");  // V_kt done + P visible; K(kt+1) flying
    __builtin_amdgcn_sched_barrier(0);
    __builtin_amdgcn_s_barrier();
    __builtin_amdgcn_sched_barrier(0);

    // PV: O[64q x 64d-slice] += P * V
    #pragma unroll
    for (int ks = 0; ks < 4; ++ks) {
      short8 pf0 = *(const short8*)((const char*)Pb + ((ks * 2048 + l31 * 32 + l5 * 16) ^ pswz));
      short8 pf1 = *(const short8*)((const char*)Pb + ((ks * 2048 + (32 + l31) * 32 + l5 * 16) ^ pswz));
      short8 vf0 = *(const short8*)((const char*)Vb + ks * 8192 + (d0 + l31) * 32 + l5 * 16);
      short8 vf1 = *(const short8*)((const char*)Vb + ks * 8192 + (d0 + 32 + l31) * 32 + l5 * 16);
      oacc[0][0] = mfma32(pf0, vf0, oacc[0][0]);
      oacc[0][1] = mfma32(pf0, vf1, oacc[0][1]);
      oacc[1][0] = mfma32(pf1, vf0, oacc[1][0]);
      oacc[1][1] = mfma32(pf1, vf1, oacc[1][1]);
    }

    asm volatile("s_waitcnt lgkmcnt(0)" ::: "memory");  // all Vb/Pb reads done
    __builtin_amdgcn_sched_barrier(0);
    __builtin_amdgcn_s_barrier();
    __builtin_amdgcn_sched_barrier(0);

    // stage V(kt+1) into the (now free) single V buffer
    {
      const char* src = vsrc + ((size_t)(kt + 1) << 15);
      #pragma unroll
      for (int m = 0; m < 8; ++m) { int s = m * 256 + tid; g2l16((char*)Vb + s * 16, src + s * 16); }
    }

    asm volatile("s_waitcnt vmcnt(8)" ::: "memory");    // K(kt+1) ready; V(kt+1) flying
    __builtin_amdgcn_sched_barrier(0);
    __builtin_amdgcn_s_barrier();
    __builtin_amdgcn_sched_barrier(0);
  }

  // epilogue: O stores
  #pragma unroll
  for (int qg2 = 0; qg2 < 2; ++qg2)
    #pragma unroll
    for (int dg = 0; dg < 2; ++dg)
      #pragma unroll
      for (int reg = 0; reg < 16; ++reg) {
        int qg = q0 + qg2 * 32 + (reg & 3) + 8 * (reg >> 2) + 4 * l5;
        int dd = d0 + dg * 32 + l31;
        if (qg < S_) out[((size_t)b * S_ + qg) * D_ + dd] = oacc[qg2][dg][reg];
      }
}

extern "C" void kernel_launch(void* const* d_in, const int* in_sizes, int n_in,
                              void* d_out, int out_size, void* d_ws, size_t ws_size,
                              hipStream_t stream) {
  (void)in_sizes; (void)n_in; (void)out_size; (void)ws_size;
  const float* src   = (const float*)d_in[0];
  const float* learn = (const float*)d_in[1];
  const float* Wtq = (const float*)d_in[2];
  const float* Wtk = (const float*)d_in[3];
  const float* Wtv = (const float*)d_in[4];
  const float* Wvq = (const float*)d_in[5];
  const float* Wvk = (const float*)d_in[6];
  const float* Wvv = (const float*)d_in[7];
  float* out = (float*)d_out;

  char* ws = (char*)d_ws;
  const size_t QKV_ONE = (size_t)B_ * SP * D_ * 2;          // 17,825,792 B each (NKT*32KB == SP*256*2)
  const size_t QP_OFF  = 0;
  const size_t KS_OFF  = QP_OFF + QKV_ONE;
  const size_t VT_OFF  = KS_OFF + QKV_ONE;
  const size_t SIG_OFF = VT_OFF + QKV_ONE;                  // 53,477,376
  const size_t TBL_OFF = SIG_OFF + (size_t)VID * VID * 2;   // +8,388,608
  const size_t WT_OFF  = TBL_OFF + (size_t)VID * 128 * 4 * sizeof(float); // +4,194,304

  ushort_t* Qp   = (ushort_t*)(ws + QP_OFF);
  ushort_t* Ks   = (ushort_t*)(ws + KS_OFF);
  ushort_t* VTs  = (ushort_t*)(ws + VT_OFF);
  ushort_t* sigp = (ushort_t*)(ws + SIG_OFF);
  float*    tbl  = (float*)(ws + TBL_OFF);
  ushort_t* WT   = (ushort_t*)(ws + WT_OFF);

  float* loss = out + (size_t)B_ * S_ * D_;

  hipMemsetAsync(ws, 0, SIG_OFF, stream);          // zero Q/Ks/VTs (padding tiles)
  hipMemsetAsync(loss, 0, sizeof(float), stream);

  tbl_kernel<<<1024, 256, 0, stream>>>(tbl);
  sig_loss_kernel<<<2048, 256, 0, stream>>>(learn, sigp, loss);
  wt_kernel<<<dim3(4, 4, 3), 256, 0, stream>>>(Wvq, Wvk, Wvv, WT);
  txt_kernel<<<dim3(4, B_), 256, 0, stream>>>(src, Wtq, Wtk, Wtv, Qp, Ks, VTs);
  vid_gemm<<<dim3(32, B_, 12), 256, 0, stream>>>(src, WT, tbl, Qp, Ks, VTs);
  attn_kernel<<<dim3(528), 256, 0, stream>>>(Qp, Ks, VTs, sigp, out);
}

// Round 4
// 339.885 us; speedup vs baseline: 2.9323x; 2.1982x over previous
//
#include <hip/hip_runtime.h>

#define B_   16
#define TXT  32
#define VID  2048
#define D_   256
#define S_   2080
#define SP   2176   // padded sequence rows for Q
#define NKT  34     // kv tiles (64 each) in K/V layouts
#define ITERS 33    // kv tiles actually processed (covers 2112 >= 2080)

typedef unsigned short ushort_t;
typedef __attribute__((ext_vector_type(8))) short short8;
typedef __attribute__((ext_vector_type(4))) short short4v;
typedef __attribute__((ext_vector_type(4))) float f32x4;
typedef __attribute__((ext_vector_type(16))) float f32x16;

__device__ __forceinline__ ushort_t f2bf(float f) {
  unsigned u = __builtin_bit_cast(unsigned, f);
  unsigned r = (u + 0x7FFFu + ((u >> 16) & 1u)) >> 16;   // RNE (finite values)
  return (ushort_t)r;
}
__device__ __forceinline__ float bf2f(ushort_t h) {
  unsigned u = ((unsigned)h) << 16;
  return __builtin_bit_cast(float, u);
}

__device__ __forceinline__ void g2l16(void* lds, const void* g) {
  __builtin_amdgcn_global_load_lds(
      (const __attribute__((address_space(1))) char*)g,
      (__attribute__((address_space(3))) char*)lds, 16, 0, 0);
}

__device__ __forceinline__ f32x4 mfma16(short8 a, short8 b, f32x4 c) {
  return __builtin_amdgcn_mfma_f32_16x16x32_bf16(a, b, c, 0, 0, 0);
}
__device__ __forceinline__ f32x16 mfma32(short8 a, short8 b, f32x16 c) {
  return __builtin_amdgcn_mfma_f32_32x32x16_bf16(a, b, c, 0, 0, 0);
}

// K layout (per batch, per 64-kv tile, 32KB):   [kstep16][64 kv][16 us]   (d-chunk rows of 32B)
// V layout (per batch, per 64-kv tile, 32KB):   [kvstep4][256 d][16 us]   (kv-chunk rows of 32B)
// tile base (ushorts): (b*NKT + ktile) << 14

// ---------------- xpos table: [2048][128] x {cos*s, sin*s, cos/s, sin/s} ----------------
__global__ void tbl_kernel(float* __restrict__ tbl) {
  int idx = blockIdx.x * 256 + threadIdx.x;     // 2048*128 = 262144
  int n = idx >> 7, i = idx & 127;
  float invf = powf(10000.0f, -(float)i / 128.0f);
  float ang = (float)n * invf;
  float s, co;
  sincosf(ang, &s, &co);
  float sv = ((float)(2 * i) + 102.4f) / 358.4f;   // (2i + 0.4*256)/(1.4*256)
  float sc = powf(sv, (float)n / 512.0f);
  float4 r;
  r.x = co * sc; r.y = s * sc; r.z = co / sc; r.w = s / sc;
  *(float4*)(tbl + (size_t)idx * 4) = r;
}

// ---------------- sigmoid mask (bf16) + sparsity loss ----------------
__global__ void sig_loss_kernel(const float* __restrict__ learn, ushort_t* __restrict__ sigp,
                                float* __restrict__ loss) {
  const int tid = threadIdx.x;
  const int base = (blockIdx.x * 256 + tid) * 8;
  float4 v0 = *(const float4*)(learn + base);
  float4 v1 = *(const float4*)(learn + base + 4);
  float vals[8] = {v0.x, v0.y, v0.z, v0.w, v1.x, v1.y, v1.z, v1.w};
  float acc = 0.f;
  short8 sh;
  #pragma unroll
  for (int j = 0; j < 8; ++j) {
    int idx = base + j;
    float s = 1.0f / (1.0f + expf(-vals[j]));
    sh[j] = (short)f2bf(s);
    int rr = idx >> 11, cc = idx & 2047;
    if (rr != cc) acc += s;
  }
  *(short8*)(sigp + base) = sh;
  __shared__ float red[256];
  red[tid] = acc;
  __syncthreads();
  #pragma unroll
  for (int st = 128; st > 0; st >>= 1) {
    if (tid < st) red[tid] += red[tid + st];
    __syncthreads();
  }
  if (tid == 0) atomicAdd(loss, red[0] * (1.0f / 4194304.0f));
}

// ---------------- weight transpose: WT[mat][n][k] = W[k][n] (bf16) ----------------
__global__ void wt_kernel(const float* __restrict__ Wq, const float* __restrict__ Wk,
                          const float* __restrict__ Wv, ushort_t* __restrict__ WT) {
  __shared__ float t[64][68];
  const int k0 = blockIdx.x * 64, n0 = blockIdx.y * 64, mt = blockIdx.z;
  const float* W = (mt == 0) ? Wq : (mt == 1) ? Wk : Wv;
  int tid = threadIdx.x;
  int r = tid >> 4, cq = (tid & 15) * 4;
  #pragma unroll
  for (int m = 0; m < 4; ++m) {
    int k = m * 16 + r;
    float4 v = *(const float4*)(W + (size_t)(k0 + k) * 256 + n0 + cq);
    t[k][cq] = v.x; t[k][cq + 1] = v.y; t[k][cq + 2] = v.z; t[k][cq + 3] = v.w;
  }
  __syncthreads();
  #pragma unroll
  for (int m = 0; m < 4; ++m) {
    int n = m * 16 + r;
    short4v h;
    h[0] = (short)f2bf(t[cq + 0][n]);
    h[1] = (short)f2bf(t[cq + 1][n]);
    h[2] = (short)f2bf(t[cq + 2][n]);
    h[3] = (short)f2bf(t[cq + 3][n]);
    *(short4v*)(WT + ((size_t)mt * D_ + n0 + n) * D_ + k0 + cq) = h;
  }
}

// ---------------- txt rows: Q/K = (pos+x)W, V = xW ----------------
__global__ void txt_kernel(const float* __restrict__ src,
                           const float* __restrict__ Wq, const float* __restrict__ Wk,
                           const float* __restrict__ Wv,
                           ushort_t* __restrict__ Qp, ushort_t* __restrict__ Ks,
                           ushort_t* __restrict__ VTs) {
  __shared__ float a_s[8][256];
  __shared__ float x_s[8][256];
  const int tg = blockIdx.x;       // 0..3  (8 rows each)
  const int b  = blockIdx.y;
  const int c  = threadIdx.x;      // 0..255
  #pragma unroll
  for (int t = 0; t < 8; ++t) {
    int row = tg * 8 + t;
    float x = src[((size_t)b * S_ + row) * D_ + c];
    float xe = (float)(row + 1) * (6.283185307179586f / (32.0f + 1e-6f));
    int i = c >> 1;
    float dimt = powf(10000.0f, (2.0f * (float)i) / 256.0f);
    float ang = xe / dimt;
    float pv = (c & 1) ? cosf(ang) : sinf(ang);
    x_s[t][c] = x;
    a_s[t][c] = x + pv;
  }
  __syncthreads();
  float q[8] = {0,0,0,0,0,0,0,0}, k[8] = {0,0,0,0,0,0,0,0}, v[8] = {0,0,0,0,0,0,0,0};
  for (int kk = 0; kk < 256; ++kk) {
    float wq = Wq[(size_t)kk * 256 + c];
    float wk = Wk[(size_t)kk * 256 + c];
    float wv = Wv[(size_t)kk * 256 + c];
    #pragma unroll
    for (int t = 0; t < 8; ++t) {
      q[t] = fmaf(a_s[t][kk], wq, q[t]);
      k[t] = fmaf(a_s[t][kk], wk, k[t]);
      v[t] = fmaf(x_s[t][kk], wv, v[t]);
    }
  }
  #pragma unroll
  for (int t = 0; t < 8; ++t) {
    int row = tg * 8 + t;          // kv row (txt rows are kv 0..31, ktile 0)
    Qp[((size_t)b * SP + row) * D_ + c] = f2bf(q[t]);
    Ks[(((size_t)(b * NKT)) << 14) + (c >> 4) * 1024 + row * 16 + (c & 15)] = f2bf(k[t]);
    VTs[(((size_t)(b * NKT)) << 14) + (row >> 4) * 4096 + c * 16 + (row & 15)] = f2bf(v[t]);
  }
}

// ---------------- vid projection GEMM (+xpos epilogue, subtiled K/V out) ----------------
__global__ __launch_bounds__(256, 2) void vid_gemm(
    const float* __restrict__ src, const ushort_t* __restrict__ WT,
    const float* __restrict__ tbl,
    ushort_t* __restrict__ Qp, ushort_t* __restrict__ Ks, ushort_t* __restrict__ VTs) {
  __shared__ __align__(16) ushort_t ldsA[64 * 64];
  __shared__ __align__(16) ushort_t ldsB[64 * 64];

  const int rt = blockIdx.x;            // 0..31 row tiles (vid rows)
  const int b  = blockIdx.y;
  const int ct = blockIdx.z;            // 0..11 col tiles (3 mats x 4)
  const int nt = ct >> 2;
  const int n0 = (ct & 3) * 64;
  const int tid = threadIdx.x;
  const int wv = tid >> 6, lane = tid & 63, l15 = lane & 15, l4 = lane >> 4;

  f32x4 acc[4];
  #pragma unroll
  for (int t2 = 0; t2 < 4; ++t2) { acc[t2][0] = 0.f; acc[t2][1] = 0.f; acc[t2][2] = 0.f; acc[t2][3] = 0.f; }

  for (int kk = 0; kk < 256; kk += 64) {
    #pragma unroll
    for (int m = 0; m < 4; ++m) {                 // A tile 64x64 (f32->bf16, swizzled)
      int q = m * 256 + tid;
      int r = q >> 4;
      int kc = (q & 15) * 4;
      const float4 v = *(const float4*)(src + ((size_t)b * S_ + TXT + rt * 64 + r) * D_ + kk + kc);
      short4v h;
      h[0] = (short)f2bf(v.x); h[1] = (short)f2bf(v.y);
      h[2] = (short)f2bf(v.z); h[3] = (short)f2bf(v.w);
      int off = ((r << 7) + (kc << 1)) ^ ((r & 7) << 4);
      *(short4v*)((char*)ldsA + off) = h;
    }
    #pragma unroll
    for (int m = 0; m < 2; ++m) {                 // B^T tile 64x64 via global_load_lds
      int p = (m * 256 + tid) * 16;
      int nl = p >> 7;
      int c = (p & 127) ^ ((nl & 7) << 4);
      g2l16((char*)ldsB + p, (const char*)(WT + ((size_t)nt * D_ + n0 + nl) * D_ + kk) + c);
    }
    __syncthreads();
    #pragma unroll
    for (int ks = 0; ks < 2; ++ks) {
      int ar = wv * 16 + l15;
      int aoff = ((ar << 7) + ((ks * 32 + l4 * 8) << 1)) ^ ((ar & 7) << 4);
      short8 av = *(const short8*)((const char*)ldsA + aoff);
      #pragma unroll
      for (int t2 = 0; t2 < 4; ++t2) {
        int nl = t2 * 16 + l15;
        int boff = ((nl << 7) + ((ks * 32 + l4 * 8) << 1)) ^ ((nl & 7) << 4);
        short8 bv = *(const short8*)((const char*)ldsB + boff);
        acc[t2] = mfma16(av, bv, acc[t2]);
      }
    }
    __syncthreads();
  }

  const int rowl = wv * 16 + l4 * 4;
  if (nt < 2) {
    // xpos rotary epilogue; even col: x*cs - x_partner*ss ; odd: x*cs + x_partner*ss
    #pragma unroll
    for (int t2 = 0; t2 < 4; ++t2) {
      int c = n0 + t2 * 16 + l15;
      #pragma unroll
      for (int r = 0; r < 4; ++r) {
        int n = rt * 64 + rowl + r;          // vid position 0..2047
        float x = acc[t2][r];
        float xp = __shfl_xor(x, 1);
        const float4 tb = *(const float4*)(tbl + ((size_t)n * 128 + (c >> 1)) * 4);
        float cs = (nt == 0) ? tb.x : tb.z;
        float ss = (nt == 0) ? tb.y : tb.w;
        float val = (c & 1) ? fmaf(x, cs, xp * ss) : fmaf(x, cs, -xp * ss);
        if (nt == 0) {
          Qp[((size_t)b * SP + TXT + n) * D_ + c] = f2bf(val);
        } else {
          int kvg = TXT + n;
          Ks[(((size_t)(b * NKT + (kvg >> 6))) << 14) + (c >> 4) * 1024 + (kvg & 63) * 16 + (c & 15)] = f2bf(val);
        }
      }
    }
  } else {
    // V: transpose via LDS then coalesced store to subtiled VTs
    #pragma unroll
    for (int t2 = 0; t2 < 4; ++t2)
      #pragma unroll
      for (int r = 0; r < 4; ++r) {
        int rr = rowl + r;
        int cc = t2 * 16 + l15;
        int off = ((rr << 7) + (cc << 1)) ^ ((rr & 7) << 4);
        *(ushort_t*)((char*)ldsA + off) = f2bf(acc[t2][r]);
      }
    __syncthreads();
    int n = tid >> 2;                 // local d 0..63
    int rc = (tid & 3) * 16;          // local vid row chunk
    short8 o0, o1;
    #pragma unroll
    for (int j = 0; j < 8; ++j) {
      int rr = rc + j;
      int off = ((rr << 7) + (n << 1)) ^ ((rr & 7) << 4);
      o0[j] = *(const short*)((const char*)ldsA + off);
    }
    #pragma unroll
    for (int j = 0; j < 8; ++j) {
      int rr = rc + 8 + j;
      int off = ((rr << 7) + (n << 1)) ^ ((rr & 7) << 4);
      o1[j] = *(const short*)((const char*)ldsA + off);
    }
    int d = n0 + n;
    int kvg0 = TXT + rt * 64 + rc;    // 16-aligned
    size_t base = (((size_t)(b * NKT + (kvg0 >> 6))) << 14) + ((kvg0 >> 4) & 3) * 4096 + d * 16;
    *(short8*)(VTs + base) = o0;
    *(short8*)(VTs + base + 8) = o1;
  }
}

// ---------------- fused masked attention: out = (Q K^T * M) V ----------------
// 4 waves, 72KB LDS -> 2 blocks/CU (8 waves/CU, 2/SIMD) for cross-block latency hiding.
// Single K buf + single V buf (just-in-time overwrite after barrier), P 8KB.
// Counted vmcnt pipeline: K(t+1) staged during PV, V(t+1)+masks(t+1) during next QK.
__global__ __launch_bounds__(256, 2) void attn_kernel(
    const ushort_t* __restrict__ Qp, const ushort_t* __restrict__ Ks,
    const ushort_t* __restrict__ VTs, const ushort_t* __restrict__ sigp,
    float* __restrict__ out) {
  __shared__ __align__(16) ushort_t Kb[16384];      // 32KB  K(t)
  __shared__ __align__(16) ushort_t Vb[16384];      // 32KB  V(t)
  __shared__ __align__(16) ushort_t Pb[4096];       // 8KB   [ks4][64 q][16 us], XOR swz

  const int flat = blockIdx.x;                      // 528 = 8 * 66, bijective XCD swizzle
  const int wg = (flat & 7) * 66 + (flat >> 3);
  const int b  = wg / ITERS;
  const int qt = wg % ITERS;
  const int tid = threadIdx.x;
  const int wid = tid >> 6, lane = tid & 63;
  const int l31 = lane & 31, l5 = lane >> 5;
  const int qh = wid >> 1, kh = wid & 1, d0 = wid * 64;
  const int q0 = qt * 64;

  // static Q fragments: rows q0+qh*32+l31, k-chunks per kstep
  short8 qf[16];
  {
    const ushort_t* qrow = Qp + ((size_t)b * SP + q0 + qh * 32 + l31) * D_ + l5 * 8;
    #pragma unroll
    for (int ks = 0; ks < 16; ++ks) qf[ks] = *(const short8*)(qrow + ks * 16);
  }

  f32x16 oacc[2][2];
  #pragma unroll
  for (int i = 0; i < 2; ++i)
    #pragma unroll
    for (int j = 0; j < 2; ++j)
      #pragma unroll
      for (int r = 0; r < 16; ++r) oacc[i][j][r] = 0.f;

  const char* ksrc = (const char*)Ks + (((size_t)(b * NKT)) << 15);
  const char* vsrc = (const char*)VTs + (((size_t)(b * NKT)) << 15);

  ushort_t mvu[16];
  // mask loader for tile t (raw bf16; validity recomputed at use)
  auto ldmask = [&](int t) {
    unsigned ki = (unsigned)(t * 64 + kh * 32 + l31 - TXT);
    bool kok = ki < (unsigned)VID;
    #pragma unroll
    for (int r = 0; r < 16; ++r) {
      int qloc = qh * 32 + (r & 3) + 8 * (r >> 2) + 4 * l5;
      unsigned qi = (unsigned)(q0 + qloc - TXT);
      bool ok = kok && (qi < (unsigned)VID);
      mvu[r] = sigp[ok ? ((size_t)qi * VID + ki) : 0];
    }
  };

  // prologue: K0 (oldest 8), masks(0) (16), V0 (8); wait K0 via vmcnt(24)
  #pragma unroll
  for (int m = 0; m < 8; ++m) { int s = m * 256 + tid; g2l16((char*)Kb + s * 16, ksrc + s * 16); }
  __builtin_amdgcn_sched_barrier(0);
  ldmask(0);
  __builtin_amdgcn_sched_barrier(0);
  #pragma unroll
  for (int m = 0; m < 8; ++m) { int s = m * 256 + tid; g2l16((char*)Vb + s * 16, vsrc + s * 16); }
  __builtin_amdgcn_sched_barrier(0);
  asm volatile("s_waitcnt vmcnt(24)" ::: "memory");
  __builtin_amdgcn_sched_barrier(0);
  __builtin_amdgcn_s_barrier();
  __builtin_amdgcn_sched_barrier(0);

  for (int kt = 0; kt < ITERS; ++kt) {
    // ---- QK: S quarter, 2 independent accumulator chains ----
    f32x16 s0, s1;
    #pragma unroll
    for (int r = 0; r < 16; ++r) { s0[r] = 0.f; s1[r] = 0.f; }
    const int krow = (kh * 32 + l31) * 32 + l5 * 16;
    __builtin_amdgcn_s_setprio(1);
    #pragma unroll
    for (int ks = 0; ks < 8; ++ks) {
      short8 kfa = *(const short8*)((const char*)Kb + ks * 2048 + krow);
      short8 kfb = *(const short8*)((const char*)Kb + (ks + 8) * 2048 + krow);
      s0 = mfma32(qf[ks], kfa, s0);
      s1 = mfma32(qf[ks + 8], kfb, s1);
    }
    __builtin_amdgcn_s_setprio(0);

    // ---- mask + P write (bf16, swizzled; masks preloaded last iter) ----
    {
      unsigned ki = (unsigned)(kt * 64 + kh * 32 + l31 - TXT);
      bool kok = ki < (unsigned)VID;
      const int kvl = kh * 32 + l31;
      const int ksp = kvl >> 4;
      #pragma unroll
      for (int r = 0; r < 16; ++r) {
        int qloc = qh * 32 + (r & 3) + 8 * (r >> 2) + 4 * l5;
        unsigned qi = (unsigned)(q0 + qloc - TXT);
        float mvf = (kok && qi < (unsigned)VID) ? bf2f(mvu[r]) : 1.0f;
        float sv = (s0[r] + s1[r]) * mvf;
        int off = (ksp * 2048 + qloc * 32 + (kvl & 15) * 2)
                  ^ ((((unsigned)qloc >> 2) & 3) << 5) ^ ((ksp & 1) << 6);
        *(ushort_t*)((char*)Pb + off) = f2bf(sv);
      }
    }

    asm volatile("s_waitcnt vmcnt(0) lgkmcnt(0)" ::: "memory");  // V(t) landed; P visible
    __builtin_amdgcn_sched_barrier(0);
    __builtin_amdgcn_s_barrier();          // barrier 1: K reads done block-wide
    __builtin_amdgcn_sched_barrier(0);

    // stage K(t+1) into Kb (free now; tile ITERS is zero padding)
    {
      const char* src = ksrc + ((size_t)(kt + 1) << 15);
      #pragma unroll
      for (int m = 0; m < 8; ++m) { int s = m * 256 + tid; g2l16((char*)Kb + s * 16, src + s * 16); }
    }
    __builtin_amdgcn_sched_barrier(0);

    // ---- PV: O[64q x 64d-slice] += P * V ----
    __builtin_amdgcn_s_setprio(1);
    #pragma unroll
    for (int ks = 0; ks < 4; ++ks) {
      int p0 = (ks * 2048 + l31 * 32 + l5 * 16) ^ ((((unsigned)l31 >> 2) & 3) << 5) ^ ((ks & 1) << 6);
      int p1 = (ks * 2048 + (32 + l31) * 32 + l5 * 16) ^ ((((unsigned)(32 + l31) >> 2) & 3) << 5) ^ ((ks & 1) << 6);
      short8 pf0 = *(const short8*)((const char*)Pb + p0);
      short8 pf1 = *(const short8*)((const char*)Pb + p1);
      short8 vf0 = *(const short8*)((const char*)Vb + ks * 8192 + (d0 + l31) * 32 + l5 * 16);
      short8 vf1 = *(const short8*)((const char*)Vb + ks * 8192 + (d0 + 32 + l31) * 32 + l5 * 16);
      oacc[0][0] = mfma32(pf0, vf0, oacc[0][0]);
      oacc[0][1] = mfma32(pf0, vf1, oacc[0][1]);
      oacc[1][0] = mfma32(pf1, vf0, oacc[1][0]);
      oacc[1][1] = mfma32(pf1, vf1, oacc[1][1]);
    }
    __builtin_amdgcn_s_setprio(0);
    __builtin_amdgcn_sched_barrier(0);
    __builtin_amdgcn_s_barrier();          // barrier 2: V/P reads done block-wide
    __builtin_amdgcn_sched_barrier(0);

    // masks(t+1) (older than V-stage so their wait leaves V flying)
    ldmask(kt + 1);
    __builtin_amdgcn_sched_barrier(0);
    // stage V(t+1) into Vb
    {
      const char* src = vsrc + ((size_t)(kt + 1) << 15);
      #pragma unroll
      for (int m = 0; m < 8; ++m) { int s = m * 256 + tid; g2l16((char*)Vb + s * 16, src + s * 16); }
    }
    __builtin_amdgcn_sched_barrier(0);
    asm volatile("s_waitcnt vmcnt(24)" ::: "memory");   // K(t+1) done; masks+V flying
    __builtin_amdgcn_sched_barrier(0);
    __builtin_amdgcn_s_barrier();          // barrier 3: K(t+1) ready block-wide
    __builtin_amdgcn_sched_barrier(0);
  }

  // epilogue: O stores
  #pragma unroll
  for (int qg2 = 0; qg2 < 2; ++qg2)
    #pragma unroll
    for (int dg = 0; dg < 2; ++dg)
      #pragma unroll
      for (int reg = 0; reg < 16; ++reg) {
        int qg = q0 + qg2 * 32 + (reg & 3) + 8 * (reg >> 2) + 4 * l5;
        int dd = d0 + dg * 32 + l31;
        if (qg < S_) out[((size_t)b * S_ + qg) * D_ + dd] = oacc[qg2][dg][reg];
      }
}

extern "C" void kernel_launch(void* const* d_in, const int* in_sizes, int n_in,
                              void* d_out, int out_size, void* d_ws, size_t ws_size,
                              hipStream_t stream) {
  (void)in_sizes; (void)n_in; (void)out_size; (void)ws_size;
  const float* src   = (const float*)d_in[0];
  const float* learn = (const float*)d_in[1];
  const float* Wtq = (const float*)d_in[2];
  const float* Wtk = (const float*)d_in[3];
  const float* Wtv = (const float*)d_in[4];
  const float* Wvq = (const float*)d_in[5];
  const float* Wvk = (const float*)d_in[6];
  const float* Wvv = (const float*)d_in[7];
  float* out = (float*)d_out;

  char* ws = (char*)d_ws;
  const size_t QKV_ONE = (size_t)B_ * SP * D_ * 2;          // 17,825,792 B each (NKT*32KB == SP*256*2)
  const size_t QP_OFF  = 0;
  const size_t KS_OFF  = QP_OFF + QKV_ONE;
  const size_t VT_OFF  = KS_OFF + QKV_ONE;
  const size_t SIG_OFF = VT_OFF + QKV_ONE;                  // 53,477,376
  const size_t TBL_OFF = SIG_OFF + (size_t)VID * VID * 2;   // +8,388,608
  const size_t WT_OFF  = TBL_OFF + (size_t)VID * 128 * 4 * sizeof(float); // +4,194,304

  ushort_t* Qp   = (ushort_t*)(ws + QP_OFF);
  ushort_t* Ks   = (ushort_t*)(ws + KS_OFF);
  ushort_t* VTs  = (ushort_t*)(ws + VT_OFF);
  ushort_t* sigp = (ushort_t*)(ws + SIG_OFF);
  float*    tbl  = (float*)(ws + TBL_OFF);
  ushort_t* WT   = (ushort_t*)(ws + WT_OFF);

  float* loss = out + (size_t)B_ * S_ * D_;

  hipMemsetAsync(ws, 0, SIG_OFF, stream);          // zero Q/Ks/VTs (padding tiles)
  hipMemsetAsync(loss, 0, sizeof(float), stream);

  tbl_kernel<<<1024, 256, 0, stream>>>(tbl);
  sig_loss_kernel<<<2048, 256, 0, stream>>>(learn, sigp, loss);
  wt_kernel<<<dim3(4, 4, 3), 256, 0, stream>>>(Wvq, Wvk, Wvv, WT);
  txt_kernel<<<dim3(4, B_), 256, 0, stream>>>(src, Wtq, Wtk, Wtv, Qp, Ks, VTs);
  vid_gemm<<<dim3(32, B_, 12), 256, 0, stream>>>(src, WT, tbl, Qp, Ks, VTs);
  attn_kernel<<<dim3(528), 256, 0, stream>>>(Qp, Ks, VTs, sigp, out);
}

// Round 5
// 298.127 us; speedup vs baseline: 3.3431x; 1.1401x over previous
//
#include <hip/hip_runtime.h>

#define B_   16
#define TXT  32
#define VID  2048
#define D_   256
#define S_   2080
#define SP   2176   // padded sequence rows for Q
#define NKT  34     // kv tiles (64 each) in K/V layouts
#define GTOT 17424  // 16 b * 33 qt * 33 kv global iterations

typedef unsigned short ushort_t;
typedef __attribute__((ext_vector_type(8))) short short8;
typedef __attribute__((ext_vector_type(4))) short short4v;
typedef __attribute__((ext_vector_type(4))) float f32x4;
typedef __attribute__((ext_vector_type(16))) float f32x16;

__device__ __forceinline__ ushort_t f2bf(float f) {
  unsigned u = __builtin_bit_cast(unsigned, f);
  unsigned r = (u + 0x7FFFu + ((u >> 16) & 1u)) >> 16;   // RNE (finite values)
  return (ushort_t)r;
}
__device__ __forceinline__ float bf2f(ushort_t h) {
  unsigned u = ((unsigned)h) << 16;
  return __builtin_bit_cast(float, u);
}

__device__ __forceinline__ void g2l16(void* lds, const void* g) {
  __builtin_amdgcn_global_load_lds(
      (const __attribute__((address_space(1))) char*)g,
      (__attribute__((address_space(3))) char*)lds, 16, 0, 0);
}

__device__ __forceinline__ f32x4 mfma16(short8 a, short8 b, f32x4 c) {
  return __builtin_amdgcn_mfma_f32_16x16x32_bf16(a, b, c, 0, 0, 0);
}
__device__ __forceinline__ f32x16 mfma32(short8 a, short8 b, f32x16 c) {
  return __builtin_amdgcn_mfma_f32_32x32x16_bf16(a, b, c, 0, 0, 0);
}

// K layout (per batch, per 64-kv tile, 32KB):   [kstep16][64 kv][16 us]
// V layout (per batch, per 64-kv tile, 32KB):   [kvstep4][256 d][16 us]
// tile base (ushorts): (b*NKT + ktile) << 14

// ---------------- xpos table: [2048][128] x {cos*s, sin*s, cos/s, sin/s} ----------------
__global__ void tbl_kernel(float* __restrict__ tbl) {
  int idx = blockIdx.x * 256 + threadIdx.x;     // 2048*128 = 262144
  int n = idx >> 7, i = idx & 127;
  float invf = powf(10000.0f, -(float)i / 128.0f);
  float ang = (float)n * invf;
  float s, co;
  sincosf(ang, &s, &co);
  float sv = ((float)(2 * i) + 102.4f) / 358.4f;   // (2i + 0.4*256)/(1.4*256)
  float sc = powf(sv, (float)n / 512.0f);
  float4 r;
  r.x = co * sc; r.y = s * sc; r.z = co / sc; r.w = s / sc;
  *(float4*)(tbl + (size_t)idx * 4) = r;
}

// ---------------- sigmoid mask TRANSPOSED (sigT[kv][q], bf16) + sparsity loss ----------------
__global__ void sig_kernel(const float* __restrict__ learn, ushort_t* __restrict__ sigT,
                           float* __restrict__ loss) {
  __shared__ ushort_t t[64][68];
  __shared__ float red[256];
  const int bi = blockIdx.x;       // q-tile
  const int bj = blockIdx.y;       // kv-tile
  const int tid = threadIdx.x;
  const int r = tid >> 2, c0 = (tid & 3) * 16;
  const int q = bi * 64 + r;
  float acc = 0.f;
  const float* row = learn + (size_t)q * VID + bj * 64 + c0;
  #pragma unroll
  for (int j4 = 0; j4 < 4; ++j4) {
    float4 v = *(const float4*)(row + j4 * 4);
    float vv[4] = {v.x, v.y, v.z, v.w};
    #pragma unroll
    for (int j = 0; j < 4; ++j) {
      int kv = bj * 64 + c0 + j4 * 4 + j;
      float s = 1.0f / (1.0f + expf(-vv[j]));
      if (q != kv) acc += s;
      t[r][c0 + j4 * 4 + j] = f2bf(s);
    }
  }
  red[tid] = acc;
  __syncthreads();
  #pragma unroll
  for (int st = 128; st > 0; st >>= 1) {
    if (tid < st) red[tid] += red[tid + st];
    __syncthreads();
  }
  if (tid == 0) atomicAdd(loss, red[0] * (1.0f / 4194304.0f));
  // write transposed: row kv = bj*64 + r, cols q = bi*64 + c0..+15
  short8 o0, o1;
  #pragma unroll
  for (int j = 0; j < 8; ++j) o0[j] = (short)t[c0 + j][r];
  #pragma unroll
  for (int j = 0; j < 8; ++j) o1[j] = (short)t[c0 + 8 + j][r];
  ushort_t* dst = sigT + (size_t)(bj * 64 + r) * VID + bi * 64 + c0;
  *(short8*)dst = o0;
  *(short8*)(dst + 8) = o1;
}

// ---------------- zero-fill padding regions (replaces 53MB memset) ----------------
__global__ void pad0_kernel(ushort_t* __restrict__ Qp, ushort_t* __restrict__ Ks,
                            ushort_t* __restrict__ VTs) {
  int i = blockIdx.x * 256 + threadIdx.x;      // 81920 total, each writes 8 ushorts
  short8 z = {0, 0, 0, 0, 0, 0, 0, 0};
  if (i < 49152) {                             // Qp rows 2080..2175, 16 batches
    int bb = i / 3072, rem = i - bb * 3072;
    int row = 2080 + (rem >> 5), c8 = (rem & 31) * 8;
    *(short8*)(Qp + ((size_t)bb * SP + row) * D_ + c8) = z;
  } else if (i < 65536) {                      // Ks tile 32, kv rows 32..63
    int j = i - 49152; int bb = j >> 10; int rem = j & 1023;
    int kstep = rem >> 6, ch = rem & 63;
    size_t base = ((size_t)(bb * NKT + 32)) << 14;
    *(short8*)(Ks + base + kstep * 1024 + 512 + ch * 8) = z;
  } else if (i < 81920) {                      // VTs tile 32, kvsteps 2..3
    int j = i - 65536; int bb = j >> 10; int rem = j & 1023;
    size_t base = (((size_t)(bb * NKT + 32)) << 14) + 8192;
    *(short8*)(VTs + base + rem * 8) = z;
  }
}

// ---------------- weight transpose: WT[mat][n][k] = W[k][n] (bf16) ----------------
__global__ void wt_kernel(const float* __restrict__ Wq, const float* __restrict__ Wk,
                          const float* __restrict__ Wv, ushort_t* __restrict__ WT) {
  __shared__ float t[64][68];
  const int k0 = blockIdx.x * 64, n0 = blockIdx.y * 64, mt = blockIdx.z;
  const float* W = (mt == 0) ? Wq : (mt == 1) ? Wk : Wv;
  int tid = threadIdx.x;
  int r = tid >> 4, cq = (tid & 15) * 4;
  #pragma unroll
  for (int m = 0; m < 4; ++m) {
    int k = m * 16 + r;
    float4 v = *(const float4*)(W + (size_t)(k0 + k) * 256 + n0 + cq);
    t[k][cq] = v.x; t[k][cq + 1] = v.y; t[k][cq + 2] = v.z; t[k][cq + 3] = v.w;
  }
  __syncthreads();
  #pragma unroll
  for (int m = 0; m < 4; ++m) {
    int n = m * 16 + r;
    short4v h;
    h[0] = (short)f2bf(t[cq + 0][n]);
    h[1] = (short)f2bf(t[cq + 1][n]);
    h[2] = (short)f2bf(t[cq + 2][n]);
    h[3] = (short)f2bf(t[cq + 3][n]);
    *(short4v*)(WT + ((size_t)mt * D_ + n0 + n) * D_ + k0 + cq) = h;
  }
}

// ---------------- txt rows: Q/K = (pos+x)W, V = xW ----------------
__global__ void txt_kernel(const float* __restrict__ src,
                           const float* __restrict__ Wq, const float* __restrict__ Wk,
                           const float* __restrict__ Wv,
                           ushort_t* __restrict__ Qp, ushort_t* __restrict__ Ks,
                           ushort_t* __restrict__ VTs) {
  __shared__ float a_s[8][256];
  __shared__ float x_s[8][256];
  const int tg = blockIdx.x;       // 0..3  (8 rows each)
  const int b  = blockIdx.y;
  const int c  = threadIdx.x;      // 0..255
  #pragma unroll
  for (int t = 0; t < 8; ++t) {
    int row = tg * 8 + t;
    float x = src[((size_t)b * S_ + row) * D_ + c];
    float xe = (float)(row + 1) * (6.283185307179586f / (32.0f + 1e-6f));
    int i = c >> 1;
    float dimt = powf(10000.0f, (2.0f * (float)i) / 256.0f);
    float ang = xe / dimt;
    float pv = (c & 1) ? cosf(ang) : sinf(ang);
    x_s[t][c] = x;
    a_s[t][c] = x + pv;
  }
  __syncthreads();
  float q[8] = {0,0,0,0,0,0,0,0}, k[8] = {0,0,0,0,0,0,0,0}, v[8] = {0,0,0,0,0,0,0,0};
  for (int kk = 0; kk < 256; ++kk) {
    float wq = Wq[(size_t)kk * 256 + c];
    float wk = Wk[(size_t)kk * 256 + c];
    float wv = Wv[(size_t)kk * 256 + c];
    #pragma unroll
    for (int t = 0; t < 8; ++t) {
      q[t] = fmaf(a_s[t][kk], wq, q[t]);
      k[t] = fmaf(a_s[t][kk], wk, k[t]);
      v[t] = fmaf(x_s[t][kk], wv, v[t]);
    }
  }
  #pragma unroll
  for (int t = 0; t < 8; ++t) {
    int row = tg * 8 + t;          // kv row (txt rows are kv 0..31, ktile 0)
    Qp[((size_t)b * SP + row) * D_ + c] = f2bf(q[t]);
    Ks[(((size_t)(b * NKT)) << 14) + (c >> 4) * 1024 + row * 16 + (c & 15)] = f2bf(k[t]);
    VTs[(((size_t)(b * NKT)) << 14) + (row >> 4) * 4096 + c * 16 + (row & 15)] = f2bf(v[t]);
  }
}

// ---------------- vid projection GEMM (+xpos epilogue, subtiled K/V out) ----------------
__global__ __launch_bounds__(256, 2) void vid_gemm(
    const float* __restrict__ src, const ushort_t* __restrict__ WT,
    const float* __restrict__ tbl,
    ushort_t* __restrict__ Qp, ushort_t* __restrict__ Ks, ushort_t* __restrict__ VTs) {
  __shared__ __align__(16) ushort_t ldsA[64 * 64];
  __shared__ __align__(16) ushort_t ldsB[64 * 64];

  const int rt = blockIdx.x;            // 0..31 row tiles (vid rows)
  const int b  = blockIdx.y;
  const int ct = blockIdx.z;            // 0..11 col tiles (3 mats x 4)
  const int nt = ct >> 2;
  const int n0 = (ct & 3) * 64;
  const int tid = threadIdx.x;
  const int wv = tid >> 6, lane = tid & 63, l15 = lane & 15, l4 = lane >> 4;

  f32x4 acc[4];
  #pragma unroll
  for (int t2 = 0; t2 < 4; ++t2) { acc[t2][0] = 0.f; acc[t2][1] = 0.f; acc[t2][2] = 0.f; acc[t2][3] = 0.f; }

  for (int kk = 0; kk < 256; kk += 64) {
    #pragma unroll
    for (int m = 0; m < 4; ++m) {                 // A tile 64x64 (f32->bf16, swizzled)
      int q = m * 256 + tid;
      int r = q >> 4;
      int kc = (q & 15) * 4;
      const float4 v = *(const float4*)(src + ((size_t)b * S_ + TXT + rt * 64 + r) * D_ + kk + kc);
      short4v h;
      h[0] = (short)f2bf(v.x); h[1] = (short)f2bf(v.y);
      h[2] = (short)f2bf(v.z); h[3] = (short)f2bf(v.w);
      int off = ((r << 7) + (kc << 1)) ^ ((r & 7) << 4);
      *(short4v*)((char*)ldsA + off) = h;
    }
    #pragma unroll
    for (int m = 0; m < 2; ++m) {                 // B^T tile 64x64 via global_load_lds
      int p = (m * 256 + tid) * 16;
      int nl = p >> 7;
      int c = (p & 127) ^ ((nl & 7) << 4);
      g2l16((char*)ldsB + p, (const char*)(WT + ((size_t)nt * D_ + n0 + nl) * D_ + kk) + c);
    }
    __syncthreads();
    #pragma unroll
    for (int ks = 0; ks < 2; ++ks) {
      int ar = wv * 16 + l15;
      int aoff = ((ar << 7) + ((ks * 32 + l4 * 8) << 1)) ^ ((ar & 7) << 4);
      short8 av = *(const short8*)((const char*)ldsA + aoff);
      #pragma unroll
      for (int t2 = 0; t2 < 4; ++t2) {
        int nl = t2 * 16 + l15;
        int boff = ((nl << 7) + ((ks * 32 + l4 * 8) << 1)) ^ ((nl & 7) << 4);
        short8 bv = *(const short8*)((const char*)ldsB + boff);
        acc[t2] = mfma16(av, bv, acc[t2]);
      }
    }
    __syncthreads();
  }

  const int rowl = wv * 16 + l4 * 4;
  if (nt < 2) {
    // xpos rotary epilogue; even col: x*cs - x_partner*ss ; odd: x*cs + x_partner*ss
    #pragma unroll
    for (int t2 = 0; t2 < 4; ++t2) {
      int c = n0 + t2 * 16 + l15;
      #pragma unroll
      for (int r = 0; r < 4; ++r) {
        int n = rt * 64 + rowl + r;          // vid position 0..2047
        float x = acc[t2][r];
        float xp = __shfl_xor(x, 1);
        const float4 tb = *(const float4*)(tbl + ((size_t)n * 128 + (c >> 1)) * 4);
        float cs = (nt == 0) ? tb.x : tb.z;
        float ss = (nt == 0) ? tb.y : tb.w;
        float val = (c & 1) ? fmaf(x, cs, xp * ss) : fmaf(x, cs, -xp * ss);
        if (nt == 0) {
          Qp[((size_t)b * SP + TXT + n) * D_ + c] = f2bf(val);
        } else {
          int kvg = TXT + n;
          Ks[(((size_t)(b * NKT + (kvg >> 6))) << 14) + (c >> 4) * 1024 + (kvg & 63) * 16 + (c & 15)] = f2bf(val);
        }
      }
    }
  } else {
    // V: transpose via LDS then coalesced store to subtiled VTs
    #pragma unroll
    for (int t2 = 0; t2 < 4; ++t2)
      #pragma unroll
      for (int r = 0; r < 4; ++r) {
        int rr = rowl + r;
        int cc = t2 * 16 + l15;
        int off = ((rr << 7) + (cc << 1)) ^ ((rr & 7) << 4);
        *(ushort_t*)((char*)ldsA + off) = f2bf(acc[t2][r]);
      }
    __syncthreads();
    int n = tid >> 2;                 // local d 0..63
    int rc = (tid & 3) * 16;          // local vid row chunk
    short8 o0, o1;
    #pragma unroll
    for (int j = 0; j < 8; ++j) {
      int rr = rc + j;
      int off = ((rr << 7) + (n << 1)) ^ ((rr & 7) << 4);
      o0[j] = *(const short*)((const char*)ldsA + off);
    }
    #pragma unroll
    for (int j = 0; j < 8; ++j) {
      int rr = rc + 8 + j;
      int off = ((rr << 7) + (n << 1)) ^ ((rr & 7) << 4);
      o1[j] = *(const short*)((const char*)ldsA + off);
    }
    int d = n0 + n;
    int kvg0 = TXT + rt * 64 + rc;    // 16-aligned
    size_t base = (((size_t)(b * NKT + (kvg0 >> 6))) << 14) + ((kvg0 >> 4) & 3) * 4096 + d * 16;
    *(short8*)(VTs + base) = o0;
    *(short8*)(VTs + base + 8) = o1;
  }
}

// ---------------- fused masked attention: out += (Q K^T * M) V (atomic partials) ----------------
// Grid = 512 exactly (2 blocks/CU, all co-resident, no tail). Block k processes global
// kv-iterations [34k+(k>>5), 34(k+1)+((k+1)>>5)) of the 16b x 33qt x 33kv space.
// S^T via swapped mfma operands -> P written as 4x b64 (cvt_pk), masks from sigT.
__global__ __launch_bounds__(256, 2) void attn_kernel(
    const ushort_t* __restrict__ Qp, const ushort_t* __restrict__ Ks,
    const ushort_t* __restrict__ VTs, const ushort_t* __restrict__ sigT,
    float* __restrict__ out) {
  __shared__ __align__(16) ushort_t Kb[16384];      // 32KB  K(t)
  __shared__ __align__(16) ushort_t Vb[16384];      // 32KB  V(t)
  __shared__ __align__(16) ushort_t Pb[4096];       // 8KB   [64 q][64 kv] bf16, XOR swz

  const int kblk = blockIdx.x;                      // 0..511
  const int bs = (kblk & 7) * 64 + (kblk >> 3);     // XCD-chunked swizzle (bijective)
  int g = bs * 34 + (bs >> 5);
  const int gend = (bs + 1) * 34 + ((bs + 1) >> 5);

  const int tid = threadIdx.x;
  const int wid = tid >> 6, lane = tid & 63;
  const int l31 = lane & 31, l5 = lane >> 5;
  const int qh = wid >> 1, kh = wid & 1, d0 = wid * 64;

  int b = g / 1089, rem = g - b * 1089, qt = rem / 33, kvt = rem - qt * 33;

  short8 qf[16];
  auto ldq = [&](int bb, int qq) {
    const ushort_t* qrow = Qp + ((size_t)bb * SP + qq * 64 + qh * 32 + l31) * D_ + l5 * 8;
    #pragma unroll
    for (int ks = 0; ks < 16; ++ks) qf[ks] = *(const short8*)(qrow + ks * 16);
  };

  ushort_t mvu[16];
  auto ldmask = [&](int qq, int tt) {
    unsigned qi = (unsigned)(qq * 64 + qh * 32 + l31 - TXT);
    bool qok = qi < (unsigned)VID;
    #pragma unroll
    for (int r = 0; r < 16; ++r) {
      unsigned ki = (unsigned)(tt * 64 + kh * 32 + (r & 3) + 8 * (r >> 2) + 4 * l5 - TXT);
      bool ok = qok && (ki < (unsigned)VID);
      mvu[r] = sigT[ok ? ((size_t)ki * VID + qi) : 0];
    }
  };

  auto stageK = [&](int bb, int tt) {
    const char* src = (const char*)Ks + (((size_t)(bb * NKT + tt)) << 15);
    #pragma unroll
    for (int m = 0; m < 8; ++m) { int s = m * 256 + tid; g2l16((char*)Kb + s * 16, src + s * 16); }
  };
  auto stageV = [&](int bb, int tt) {
    const char* src = (const char*)VTs + (((size_t)(bb * NKT + tt)) << 15);
    #pragma unroll
    for (int m = 0; m < 8; ++m) { int s = m * 256 + tid; g2l16((char*)Vb + s * 16, src + s * 16); }
  };

  f32x16 oacc[2][2];
  #pragma unroll
  for (int i = 0; i < 2; ++i)
    #pragma unroll
    for (int j = 0; j < 2; ++j)
      #pragma unroll
      for (int r = 0; r < 16; ++r) oacc[i][j][r] = 0.f;

  auto flushO = [&](int bb, int qq) {
    #pragma unroll
    for (int qg2 = 0; qg2 < 2; ++qg2)
      #pragma unroll
      for (int dg = 0; dg < 2; ++dg)
        #pragma unroll
        for (int r = 0; r < 16; ++r) {
          int qg = qq * 64 + qg2 * 32 + (r & 3) + 8 * (r >> 2) + 4 * l5;
          int dd = d0 + dg * 32 + l31;
          if (qg < S_)
            unsafeAtomicAdd(&out[((size_t)bb * S_ + qg) * D_ + dd], oacc[qg2][dg][r]);
          oacc[qg2][dg][r] = 0.f;
        }
  };

  // prologue
  stageK(b, kvt);
  ldmask(qt, kvt);
  stageV(b, kvt);
  ldq(b, qt);
  asm volatile("s_waitcnt vmcnt(0)" ::: "memory");
  __builtin_amdgcn_sched_barrier(0);
  __builtin_amdgcn_s_barrier();
  __builtin_amdgcn_sched_barrier(0);

  while (g < gend) {
    int gn = (g + 1 < GTOT) ? g + 1 : GTOT - 1;
    int nb = gn / 1089, nrem = gn - nb * 1089, nqt = nrem / 33, nkvt = nrem - nqt * 33;

    // ---- QK (S^T = K . Q^T): 2 independent chains ----
    f32x16 s0, s1;
    #pragma unroll
    for (int r = 0; r < 16; ++r) { s0[r] = 0.f; s1[r] = 0.f; }
    const int arow = (kh * 32 + l31) * 32 + l5 * 16;
    __builtin_amdgcn_s_setprio(1);
    #pragma unroll
    for (int ks = 0; ks < 8; ++ks) {
      short8 ka = *(const short8*)((const char*)Kb + ks * 2048 + arow);
      short8 kc = *(const short8*)((const char*)Kb + (ks + 8) * 2048 + arow);
      s0 = mfma32(ka, qf[ks], s0);
      s1 = mfma32(kc, qf[ks + 8], s1);
    }
    __builtin_amdgcn_s_setprio(0);

    // ---- mask + P write (4 x b64 per lane, cvt_pk packed) ----
    {
      unsigned qi = (unsigned)(qt * 64 + qh * 32 + l31 - TXT);
      bool qok = qi < (unsigned)VID;
      const int prow = qh * 32 + l31;
      #pragma unroll
      for (int t = 0; t < 4; ++t) {
        float p[4];
        #pragma unroll
        for (int j = 0; j < 4; ++j) {
          int r = t * 4 + j;
          unsigned ki = (unsigned)(kvt * 64 + kh * 32 + j + 8 * t + 4 * l5 - TXT);
          float mvf = (qok && ki < (unsigned)VID) ? bf2f(mvu[r]) : 1.0f;
          p[j] = (s0[r] + s1[r]) * mvf;
        }
        unsigned w0, w1;
        asm("v_cvt_pk_bf16_f32 %0, %1, %2" : "=v"(w0) : "v"(p[0]), "v"(p[1]));
        asm("v_cvt_pk_bf16_f32 %0, %1, %2" : "=v"(w1) : "v"(p[2]), "v"(p[3]));
        int off = (prow * 128 + kh * 64 + t * 16 + l5 * 8) ^ ((l31 & 7) << 4);
        *(uint2*)((char*)Pb + off) = make_uint2(w0, w1);
      }
    }

    asm volatile("s_waitcnt vmcnt(0) lgkmcnt(0)" ::: "memory");  // V(t) landed; P visible
    __builtin_amdgcn_sched_barrier(0);
    __builtin_amdgcn_s_barrier();          // barrier 1: K reads done block-wide
    __builtin_amdgcn_sched_barrier(0);

    stageK(nb, nkvt);                      // K(next) into freed Kb
    __builtin_amdgcn_sched_barrier(0);

    // ---- PV: O[64q x 64d-slice] += P * V ----
    __builtin_amdgcn_s_setprio(1);
    #pragma unroll
    for (int ks = 0; ks < 4; ++ks) {
      int p0 = (l31 * 128 + ks * 32 + l5 * 16) ^ ((l31 & 7) << 4);
      int p1 = ((32 + l31) * 128 + ks * 32 + l5 * 16) ^ ((l31 & 7) << 4);
      short8 pf0 = *(const short8*)((const char*)Pb + p0);
      short8 pf1 = *(const short8*)((const char*)Pb + p1);
      short8 vf0 = *(const short8*)((const char*)Vb + ks * 8192 + (d0 + l31) * 32 + l5 * 16);
      short8 vf1 = *(const short8*)((const char*)Vb + ks * 8192 + (d0 + 32 + l31) * 32 + l5 * 16);
      oacc[0][0] = mfma32(pf0, vf0, oacc[0][0]);
      oacc[0][1] = mfma32(pf0, vf1, oacc[0][1]);
      oacc[1][0] = mfma32(pf1, vf0, oacc[1][0]);
      oacc[1][1] = mfma32(pf1, vf1, oacc[1][1]);
    }
    __builtin_amdgcn_s_setprio(0);
    asm volatile("s_waitcnt lgkmcnt(0)" ::: "memory");
    __builtin_amdgcn_sched_barrier(0);
    __builtin_amdgcn_s_barrier();          // barrier 2: V/P reads done block-wide
    __builtin_amdgcn_sched_barrier(0);

    ldmask(nqt, nkvt);
    __builtin_amdgcn_sched_barrier(0);
    if (nqt != qt || nb != b) {            // q-tile boundary (block-uniform)
      flushO(b, qt);
      ldq(nb, nqt);
    }
    __builtin_amdgcn_sched_barrier(0);
    stageV(nb, nkvt);
    __builtin_amdgcn_sched_barrier(0);
    asm volatile("s_waitcnt vmcnt(24)" ::: "memory");   // K(next) done; masks+V flying
    __builtin_amdgcn_sched_barrier(0);
    __builtin_amdgcn_s_barrier();          // barrier 3: K(next) ready block-wide
    __builtin_amdgcn_sched_barrier(0);

    b = nb; qt = nqt; kvt = nkvt; ++g;
  }

  flushO(b, qt);
}

extern "C" void kernel_launch(void* const* d_in, const int* in_sizes, int n_in,
                              void* d_out, int out_size, void* d_ws, size_t ws_size,
                              hipStream_t stream) {
  (void)in_sizes; (void)n_in; (void)ws_size;
  const float* src   = (const float*)d_in[0];
  const float* learn = (const float*)d_in[1];
  const float* Wtq = (const float*)d_in[2];
  const float* Wtk = (const float*)d_in[3];
  const float* Wtv = (const float*)d_in[4];
  const float* Wvq = (const float*)d_in[5];
  const float* Wvk = (const float*)d_in[6];
  const float* Wvv = (const float*)d_in[7];
  float* out = (float*)d_out;

  char* ws = (char*)d_ws;
  const size_t QKV_ONE = (size_t)B_ * SP * D_ * 2;          // 17,825,792 B each (NKT*32KB == SP*256*2)
  const size_t QP_OFF  = 0;
  const size_t KS_OFF  = QP_OFF + QKV_ONE;
  const size_t VT_OFF  = KS_OFF + QKV_ONE;
  const size_t SIG_OFF = VT_OFF + QKV_ONE;                  // 53,477,376
  const size_t TBL_OFF = SIG_OFF + (size_t)VID * VID * 2;   // +8,388,608
  const size_t WT_OFF  = TBL_OFF + (size_t)VID * 128 * 4 * sizeof(float); // +4,194,304

  ushort_t* Qp   = (ushort_t*)(ws + QP_OFF);
  ushort_t* Ks   = (ushort_t*)(ws + KS_OFF);
  ushort_t* VTs  = (ushort_t*)(ws + VT_OFF);
  ushort_t* sigT = (ushort_t*)(ws + SIG_OFF);
  float*    tbl  = (float*)(ws + TBL_OFF);
  ushort_t* WT   = (ushort_t*)(ws + WT_OFF);

  float* loss = out + (size_t)B_ * S_ * D_;
  (void)loss;

  hipMemsetAsync(d_out, 0, (size_t)out_size * sizeof(float), stream);  // atomic partials
  pad0_kernel<<<320, 256, 0, stream>>>(Qp, Ks, VTs);
  tbl_kernel<<<1024, 256, 0, stream>>>(tbl);
  sig_kernel<<<dim3(32, 32), 256, 0, stream>>>(learn, sigT, out + (size_t)B_ * S_ * D_);
  wt_kernel<<<dim3(4, 4, 3), 256, 0, stream>>>(Wvq, Wvk, Wvv, WT);
  txt_kernel<<<dim3(4, B_), 256, 0, stream>>>(src, Wtq, Wtk, Wtv, Qp, Ks, VTs);
  vid_gemm<<<dim3(32, B_, 12), 256, 0, stream>>>(src, WT, tbl, Qp, Ks, VTs);
  attn_kernel<<<dim3(512), 256, 0, stream>>>(Qp, Ks, VTs, sigT, out);
}